// Round 12
// baseline (1194.825 us; speedup 1.0000x reference)
//
#include <hip/hip_runtime.h>

#define GN_EPS 1e-5f

typedef _Float16 half8 __attribute__((ext_vector_type(8)));
typedef float floatx4 __attribute__((ext_vector_type(4)));

__device__ __forceinline__ float sigmoidf_(float x){ return 1.0f/(1.0f+__expf(-x)); }
__device__ __forceinline__ float bcast_(float v, int k){
  return __int_as_float(__builtin_amdgcn_readlane(__float_as_int(v), k));
}
union hu16 { unsigned short u; _Float16 f; };

// ================= CSR build (rank-fused: single atomic pass) =================
__global__ void rank_kernel(const int* __restrict__ ei, int* cnt, int* rank,
                            int E, int n){
  int i = blockIdx.x*blockDim.x+threadIdx.x;
  int tot = E + n;
  if (i >= tot) return;
  int c = (i < E) ? ei[E+i] : (i - E);
  rank[i] = atomicAdd(&cnt[c], 1);
}
__global__ __launch_bounds__(256) void scan1_kernel(const int* __restrict__ cnt,
                                                    int* loc, int* bsum,
                                                    float* __restrict__ dis, int n){
  __shared__ int s[256];
  int t = threadIdx.x, i = blockIdx.x*256 + t;
  int v = (i < n) ? cnt[i] : 0;
  if (i < n) dis[i] = rsqrtf((float)v);
  s[t] = v; __syncthreads();
  #pragma unroll
  for (int d = 1; d < 256; d <<= 1){
    int u = (t >= d) ? s[t-d] : 0; __syncthreads();
    s[t] += u; __syncthreads();
  }
  if (i < n) loc[i] = s[t] - v;
  if (t == 255) bsum[blockIdx.x] = s[255];
}
__global__ __launch_bounds__(256) void scan2_kernel(int* bsum, int nb){
  __shared__ int s[256];
  int t = threadIdx.x;
  int v = (t < nb) ? bsum[t] : 0;
  s[t] = v; __syncthreads();
  #pragma unroll
  for (int d = 1; d < 256; d <<= 1){
    int u = (t >= d) ? s[t-d] : 0; __syncthreads();
    s[t] += u; __syncthreads();
  }
  if (t < nb) bsum[t] = s[t] - v;
}
__global__ void scan3_kernel(const int* __restrict__ loc, const int* __restrict__ bsum,
                             int* rowptr, int n, int total){
  int i = blockIdx.x*blockDim.x+threadIdx.x;
  if (i < n) rowptr[i] = loc[i] + bsum[i >> 8];
  if (i == 0) rowptr[n] = total;
}
// pass 2: NO atomics — j = rowptr[c] + rank[i]; rec 6B/edge {r, c, ea(f16)}
__global__ void place_kernel(const int* __restrict__ ei, const float* __restrict__ ea,
                             const int* __restrict__ rowptr, const int* __restrict__ rank,
                             unsigned short* rec, int E, int n){
  int idx = blockIdx.x*blockDim.x+threadIdx.x;
  int tot = E + n;
  if (idx >= tot) return;
  int r, c; float v;
  if (idx < E){ r = ei[idx]; c = ei[E+idx]; v = ea[idx]; }
  else        { r = c = idx - E; v = 1.0f; }
  int j = rowptr[c] + rank[idx];
  hu16 cv; cv.f = (_Float16)v;
  size_t b3 = (size_t)j*3;
  rec[b3]   = (unsigned short)r;
  rec[b3+1] = (unsigned short)c;
  rec[b3+2] = cv.u;
}

// ================= weight repack (f16, MFMA-fragment order) =================
__global__ __launch_bounds__(256) void wprep_kernel(
    const float* __restrict__ w1, const float* __restrict__ zw,
    const float* __restrict__ rw, const float* __restrict__ hw,
    const float* __restrict__ fw, const float* __restrict__ w2,
    _Float16* __restrict__ wp){
  int idx = blockIdx.x*256 + threadIdx.x;
  if (idx < 8192){
    int t=idx>>10, kh=(idx>>9)&1, g=(idx>>7)&3, l=(idx>>3)&15, j=idx&7;
    int kg=(t>=4?64:0)+kh*32+g*8+j;
    wp[idx] = (_Float16)w1[kg*64 + (t&3)*16 + l];
  } else if (idx < 40960){
    int m=(idx-8192)>>13, k=(idx-8192)&8191;
    int t=(k>>11)&3, kh=(k>>9)&3, g=(k>>7)&3, l=(k>>3)&15, j=k&7;
    const float* W = (m==0)?zw:((m==1)?rw:((m==2)?hw:fw));
    wp[idx] = (_Float16)W[(kh*32+g*8+j)*64 + t*16 + l];
  } else if (idx < 45056){
    int k = idx-40960;
    int t=(k>>10)&3, kh=(k>>9)&1, g=(k>>7)&3, l=(k>>3)&15, j=k&7;
    wp[idx] = (_Float16)w2[(kh*32+g*8+j)*64 + t*16 + l];
  }
}

// ================= small node matvec + optional inline input-norm + fused stats =================
template<int K_IN, int C_OUT, int NORMIN, int STATS>
__global__ __launch_bounds__(256) void mm1_kernel(
    const float* __restrict__ x, const float* __restrict__ W,
    const float* __restrict__ b,
    const float* __restrict__ nstats, const float* __restrict__ nw,
    const float* __restrict__ nb, const float* __restrict__ nms,
    float* __restrict__ y, float* __restrict__ stats, int n){
  __shared__ float sW[K_IN*C_OUT];
  __shared__ float sSt[2*C_OUT];
  __shared__ float sIN[2*K_IN];
  if (STATS && threadIdx.x < 2*C_OUT) sSt[threadIdx.x] = 0.f;
  if (NORMIN && threadIdx.x < K_IN){
    int ch = threadIdx.x;
    float invN = 1.0f/(float)n;
    float mean = nstats[ch]*invN;
    float mm = mean*nms[ch];
    float var = nstats[K_IN+ch]*invN - mm*(2.0f*mean - mm);
    float inv = rsqrtf(fmaxf(var,0.f)+GN_EPS);
    float sc = inv*nw[ch];
    sIN[ch] = sc;
    sIN[K_IN+ch] = nb[ch] - mm*sc;
  }
  for (int i = threadIdx.x; i < K_IN*C_OUT; i += 256) sW[i] = W[i];
  __syncthreads();
  const int lane = threadIdx.x & 63;
  const int col  = (lane < C_OUT) ? lane : 0;
  const float bias = b[col];
  float isc = 1.f, iof = 0.f;
  if (NORMIN && lane < K_IN){ isc = sIN[lane]; iof = sIN[K_IN+lane]; }
  int wid = (blockIdx.x*256 + threadIdx.x) >> 6;
  int nw_ = (gridDim.x*256) >> 6;
  float qs = 0.f, qq = 0.f;
  for (int i = wid; i < n; i += nw_){
    float xv = (lane < K_IN) ? x[(size_t)i*K_IN + lane] : 0.0f;
    if (NORMIN) xv = fmaxf(xv*isc + iof, 0.f);
    float a0 = bias, a1 = 0.0f;
    #pragma unroll
    for (int k = 0; k < K_IN; k += 2){
      a0 += bcast_(xv, k  ) * sW[(k  )*C_OUT + col];
      a1 += bcast_(xv, k+1) * sW[(k+1)*C_OUT + col];
    }
    if (lane < C_OUT){
      float v = a0 + a1;
      y[(size_t)i*C_OUT + lane] = v;
      if (STATS){ qs += v; qq += v*v; }
    }
  }
  if (STATS){
    if (lane < C_OUT){
      atomicAdd(&sSt[lane], qs);
      atomicAdd(&sSt[C_OUT+lane], qq);
    }
    __syncthreads();
    if (threadIdx.x < 2*C_OUT) atomicAdd(&stats[threadIdx.x], sSt[threadIdx.x]);
  }
}

// ================= fused GraphNorm-apply + pq via MFMA =================
template<int RELU, int WRITE_H0>
__global__ __launch_bounds__(256) void normpq_kernel(
    const float* __restrict__ hin, float* __restrict__ hout,
    float* __restrict__ h0out,
    const float* __restrict__ stats,
    const float* __restrict__ gw, const float* __restrict__ gb,
    const float* __restrict__ gms,
    const _Float16* __restrict__ w1p, const float* __restrict__ b1,
    _Float16* __restrict__ Ph, _Float16* __restrict__ QH, int n)
{
  __shared__ _Float16 sB[8192];
  __shared__ float sSO[128];
  for (int i = threadIdx.x; i < 1024; i += 256)
    ((half8*)sB)[i] = ((const half8*)w1p)[i];
  if (threadIdx.x < 64){
    int ch = threadIdx.x;
    float invN = 1.0f/(float)n;
    float mean = stats[ch]*invN;
    float mm = mean*gms[ch];
    float var = stats[64+ch]*invN - mm*(2.0f*mean - mm);
    float inv = rsqrtf(fmaxf(var,0.f)+GN_EPS);
    float sc = inv*gw[ch];
    sSO[ch] = sc;
    sSO[64+ch] = gb[ch] - mm*sc;
  }
  __syncthreads();
  const int lane = threadIdx.x & 63;
  const int g16 = lane>>4, l16 = lane&15;
  float scA[8], ofA[8], scB[8], ofB[8];
  #pragma unroll
  for (int j = 0; j < 8; ++j){
    scA[j]=sSO[g16*8+j];    ofA[j]=sSO[64+g16*8+j];
    scB[j]=sSO[32+g16*8+j]; ofB[j]=sSO[96+g16*8+j];
  }
  float b1f[4];
  #pragma unroll
  for (int t = 0; t < 4; ++t) b1f[t] = b1[t*16 + l16];

  int wid = (blockIdx.x*blockDim.x + threadIdx.x) >> 6;
  int nw  = (gridDim.x*blockDim.x) >> 6;
  int tiles = (n + 15) >> 4;
  for (int tile = wid; tile < tiles; tile += nw){
    int base = tile*16;
    int na = min(base + l16, n-1);
    const float* hp = hin + (size_t)na*64;
    float4 a0 = *(const float4*)(hp + g16*8);
    float4 a1 = *(const float4*)(hp + g16*8 + 4);
    float4 c0 = *(const float4*)(hp + 32 + g16*8);
    float4 c1 = *(const float4*)(hp + 32 + g16*8 + 4);
    float va[8] = {a0.x,a0.y,a0.z,a0.w,a1.x,a1.y,a1.z,a1.w};
    float vb[8] = {c0.x,c0.y,c0.z,c0.w,c1.x,c1.y,c1.z,c1.w};
    half8 af0, af1;
    #pragma unroll
    for (int j = 0; j < 8; ++j){
      float v = va[j]*scA[j] + ofA[j];
      if (RELU) v = fmaxf(v, 0.f);
      va[j] = v; af0[j] = (_Float16)v;
      float u = vb[j]*scB[j] + ofB[j];
      if (RELU) u = fmaxf(u, 0.f);
      vb[j] = u; af1[j] = (_Float16)u;
    }
    float* op = hout + (size_t)na*64;
    *(float4*)(op + g16*8)       = (float4){va[0],va[1],va[2],va[3]};
    *(float4*)(op + g16*8 + 4)   = (float4){va[4],va[5],va[6],va[7]};
    *(float4*)(op + 32 + g16*8)  = (float4){vb[0],vb[1],vb[2],vb[3]};
    *(float4*)(op + 32 + g16*8+4)= (float4){vb[4],vb[5],vb[6],vb[7]};
    if (WRITE_H0){
      float* o2 = h0out + (size_t)na*64;
      *(float4*)(o2 + g16*8)       = (float4){va[0],va[1],va[2],va[3]};
      *(float4*)(o2 + g16*8 + 4)   = (float4){va[4],va[5],va[6],va[7]};
      *(float4*)(o2 + 32 + g16*8)  = (float4){vb[0],vb[1],vb[2],vb[3]};
      *(float4*)(o2 + 32 + g16*8+4)= (float4){vb[4],vb[5],vb[6],vb[7]};
    }
    *(half8*)(QH + (size_t)na*128 + 64 + g16*8) = af0;
    *(half8*)(QH + (size_t)na*128 + 96 + g16*8) = af1;

    floatx4 acc[8];
    #pragma unroll
    for (int t = 0; t < 8; ++t){
      float bv = (t < 4) ? b1f[t] : 0.0f;
      acc[t] = (floatx4){bv, bv, bv, bv};
    }
    #pragma unroll
    for (int t = 0; t < 8; ++t){
      half8 bf0 = *(const half8*)&sB[((t*2+0)*4+g16)*128 + l16*8];
      half8 bf1 = *(const half8*)&sB[((t*2+1)*4+g16)*128 + l16*8];
      acc[t] = __builtin_amdgcn_mfma_f32_16x16x32_f16(af0, bf0, acc[t], 0, 0, 0);
      acc[t] = __builtin_amdgcn_mfma_f32_16x16x32_f16(af1, bf1, acc[t], 0, 0, 0);
    }
    #pragma unroll
    for (int t = 0; t < 8; ++t)
      #pragma unroll
      for (int rg = 0; rg < 4; ++rg){
        int nd = base + g16*4 + rg;
        if (nd < n){
          if (t < 4) Ph[(size_t)nd*64  + t*16 + l16]      = (_Float16)acc[t][rg];
          else       QH[(size_t)nd*128 + (t-4)*16 + l16]  = (_Float16)acc[t][rg];
        }
      }
  }
}

// ================= fused GRU via MFMA + GraphNorm stats (+aggr & stats2 zeroing) =================
__global__ __launch_bounds__(256) void gru_mfma_kernel(
    float* __restrict__ h, float* __restrict__ aggr,
    const float* __restrict__ dis, const _Float16* __restrict__ QH,
    const _Float16* __restrict__ gwp,
    const float* __restrict__ zb, const float* __restrict__ rb,
    const float* __restrict__ hb,
    float* __restrict__ stats, int n)
{
  __shared__ _Float16 sW[3*8192];
  __shared__ _Float16 sRH[4][16][72];
  __shared__ float sSt[128];
  if (threadIdx.x < 128) sSt[threadIdx.x] = 0.f;
  if (blockIdx.x == 0 && threadIdx.x < 128) stats[128 + threadIdx.x] = 0.f;  // pre-zero fc1 stats
  for (int i = threadIdx.x; i < 3072; i += 256)
    ((half8*)sW)[i] = ((const half8*)gwp)[i];
  __syncthreads();
  const int lane = threadIdx.x & 63;
  const int g16 = lane>>4, l16 = lane&15;
  const int w = threadIdx.x >> 6;
  float zbf[4], rbf[4], hbf[4];
  #pragma unroll
  for (int t = 0; t < 4; ++t){
    zbf[t] = zb[t*16+l16]; rbf[t] = rb[t*16+l16]; hbf[t] = hb[t*16+l16];
  }
  float ssum[4] = {0,0,0,0}, ssq[4] = {0,0,0,0};
#define GW(m,t,kh) (*(const half8*)&sW[(m)*8192 + (((t)*4+(kh))*4+g16)*128 + l16*8])

  int wid = (blockIdx.x*blockDim.x + threadIdx.x) >> 6;
  int nw  = (gridDim.x*blockDim.x) >> 6;
  int tiles = (n + 15) >> 4;
  for (int tile = wid; tile < tiles; tile += nw){
    int base = tile*16;
    int na = min(base + l16, n-1);
    float dv = dis[na];
    half8 af[4];
    af[0] = *(const half8*)(QH + (size_t)na*128 + 64 + g16*8);
    af[1] = *(const half8*)(QH + (size_t)na*128 + 96 + g16*8);
    #pragma unroll
    for (int kh = 0; kh < 2; ++kh){
      float* ar = aggr + (size_t)na*64 + kh*32 + g16*8;
      float4 a0 = *(const float4*)ar;
      float4 a1 = *(const float4*)(ar+4);
      *(float4*)(ar)   = (float4){0,0,0,0};
      *(float4*)(ar+4) = (float4){0,0,0,0};
      half8 t8;
      t8[0]=(_Float16)(a0.x*dv); t8[1]=(_Float16)(a0.y*dv);
      t8[2]=(_Float16)(a0.z*dv); t8[3]=(_Float16)(a0.w*dv);
      t8[4]=(_Float16)(a1.x*dv); t8[5]=(_Float16)(a1.y*dv);
      t8[6]=(_Float16)(a1.z*dv); t8[7]=(_Float16)(a1.w*dv);
      af[2+kh] = t8;
    }
    floatx4 az[4], ar4[4];
    #pragma unroll
    for (int t = 0; t < 4; ++t){
      az[t]  = (floatx4){zbf[t], zbf[t], zbf[t], zbf[t]};
      ar4[t] = (floatx4){rbf[t], rbf[t], rbf[t], rbf[t]};
      #pragma unroll
      for (int kh = 0; kh < 4; ++kh){
        az[t]  = __builtin_amdgcn_mfma_f32_16x16x32_f16(af[kh], GW(0,t,kh), az[t],  0, 0, 0);
        ar4[t] = __builtin_amdgcn_mfma_f32_16x16x32_f16(af[kh], GW(1,t,kh), ar4[t], 0, 0, 0);
      }
    }
    float zr[16], hv[16];
    #pragma unroll
    for (int t = 0; t < 4; ++t)
      #pragma unroll
      for (int rg = 0; rg < 4; ++rg){
        int ndc = min(base + g16*4 + rg, n-1);
        float hval = h[(size_t)ndc*64 + t*16 + l16];
        float zv = sigmoidf_(az[t][rg]);
        float rv = sigmoidf_(ar4[t][rg]);
        zr[t*4+rg] = zv; hv[t*4+rg] = hval;
        sRH[w][g16*4+rg][t*16+l16] = (_Float16)(rv*hval);
      }
    asm volatile("s_waitcnt lgkmcnt(0)" ::: "memory");
    __builtin_amdgcn_sched_barrier(0);
    half8 af2_0 = *(const half8*)&sRH[w][l16][g16*8];
    half8 af2_1 = *(const half8*)&sRH[w][l16][32 + g16*8];
    floatx4 ah[4];
    #pragma unroll
    for (int t = 0; t < 4; ++t){
      ah[t] = (floatx4){hbf[t], hbf[t], hbf[t], hbf[t]};
      ah[t] = __builtin_amdgcn_mfma_f32_16x16x32_f16(af2_0, GW(2,t,0), ah[t], 0, 0, 0);
      ah[t] = __builtin_amdgcn_mfma_f32_16x16x32_f16(af2_1, GW(2,t,1), ah[t], 0, 0, 0);
      ah[t] = __builtin_amdgcn_mfma_f32_16x16x32_f16(af[2],  GW(2,t,2), ah[t], 0, 0, 0);
      ah[t] = __builtin_amdgcn_mfma_f32_16x16x32_f16(af[3],  GW(2,t,3), ah[t], 0, 0, 0);
    }
    #pragma unroll
    for (int t = 0; t < 4; ++t)
      #pragma unroll
      for (int rg = 0; rg < 4; ++rg){
        int nd = base + g16*4 + rg;
        if (nd < n){
          float hc = fmaxf(ah[t][rg], 0.f);
          float zv = zr[t*4+rg];
          float hn = (1.f - zv)*hv[t*4+rg] + zv*hc;
          h[(size_t)nd*64 + t*16 + l16] = hn;
          ssum[t] += hn; ssq[t] += hn*hn;
        }
      }
  }
#undef GW
  #pragma unroll
  for (int t = 0; t < 4; ++t){
    atomicAdd(&sSt[t*16+l16], ssum[t]);
    atomicAdd(&sSt[64+t*16+l16], ssq[t]);
  }
  __syncthreads();
  if (threadIdx.x < 128) atomicAdd(&stats[threadIdx.x], sSt[threadIdx.x]);
}

// ================= fc1 via MFMA + inline ggnn-norm on h + fused stats =================
__global__ __launch_bounds__(256) void fc1_mfma_kernel(
    const float* __restrict__ h0, const float* __restrict__ h,
    const float* __restrict__ hstats,
    const float* __restrict__ gw, const float* __restrict__ gb,
    const float* __restrict__ gms,
    const _Float16* __restrict__ fp, const float* __restrict__ b,
    float* __restrict__ out, float* __restrict__ stats, int n)
{
  __shared__ _Float16 sB[8192];
  __shared__ float sSt[128];
  __shared__ float sSO[128];
  if (threadIdx.x < 128) sSt[threadIdx.x] = 0.f;
  if (threadIdx.x < 64){
    int ch = threadIdx.x;
    float invN = 1.0f/(float)n;
    float mean = hstats[ch]*invN;
    float mm = mean*gms[ch];
    float var = hstats[64+ch]*invN - mm*(2.0f*mean - mm);
    float inv = rsqrtf(fmaxf(var,0.f)+GN_EPS);
    float sc = inv*gw[ch];
    sSO[ch] = sc;
    sSO[64+ch] = gb[ch] - mm*sc;
  }
  for (int i = threadIdx.x; i < 1024; i += 256)
    ((half8*)sB)[i] = ((const half8*)fp)[i];
  __syncthreads();
  const int lane = threadIdx.x & 63;
  const int g16 = lane>>4, l16 = lane&15;
  float bf[4];
  #pragma unroll
  for (int t = 0; t < 4; ++t) bf[t] = b[t*16+l16];
  float scH[16], ofH[16];
  #pragma unroll
  for (int j = 0; j < 8; ++j){
    scH[j]   = sSO[g16*8+j];    ofH[j]   = sSO[64+g16*8+j];
    scH[8+j] = sSO[32+g16*8+j]; ofH[8+j] = sSO[96+g16*8+j];
  }
  float ssum[4] = {0,0,0,0}, ssq[4] = {0,0,0,0};

  int wid = (blockIdx.x*blockDim.x + threadIdx.x) >> 6;
  int nw  = (gridDim.x*blockDim.x) >> 6;
  int tiles = (n + 15) >> 4;
  for (int tile = wid; tile < tiles; tile += nw){
    int base = tile*16;
    int na = min(base + l16, n-1);
    half8 af[4];
    #pragma unroll
    for (int kh = 0; kh < 4; ++kh){
      const float* sp = (kh < 2 ? h0 : h) + (size_t)na*64 + (kh&1)*32 + g16*8;
      float4 a0 = *(const float4*)sp;
      float4 a1 = *(const float4*)(sp+4);
      float v[8] = {a0.x,a0.y,a0.z,a0.w,a1.x,a1.y,a1.z,a1.w};
      half8 t8;
      if (kh < 2){
        #pragma unroll
        for (int j = 0; j < 8; ++j) t8[j] = (_Float16)v[j];
      } else {
        #pragma unroll
        for (int j = 0; j < 8; ++j)
          t8[j] = (_Float16)(v[j]*scH[(kh&1)*8+j] + ofH[(kh&1)*8+j]);
      }
      af[kh] = t8;
    }
    #pragma unroll
    for (int t = 0; t < 4; ++t){
      floatx4 acc = (floatx4){bf[t], bf[t], bf[t], bf[t]};
      #pragma unroll
      for (int kh = 0; kh < 4; ++kh)
        acc = __builtin_amdgcn_mfma_f32_16x16x32_f16(af[kh],
                *(const half8*)&sB[((t*4+kh)*4+g16)*128 + l16*8], acc, 0, 0, 0);
      #pragma unroll
      for (int rg = 0; rg < 4; ++rg){
        int nd = base + g16*4 + rg;
        if (nd < n){
          float v = acc[rg];
          out[(size_t)nd*64 + t*16 + l16] = v;
          ssum[t] += v; ssq[t] += v*v;
        }
      }
    }
  }
  #pragma unroll
  for (int t = 0; t < 4; ++t){
    atomicAdd(&sSt[t*16+l16], ssum[t]);
    atomicAdd(&sSt[64+t*16+l16], ssq[t]);
  }
  __syncthreads();
  if (threadIdx.x < 128) atomicAdd(&stats[threadIdx.x], sSt[threadIdx.x]);
}

// ================= edge kernel: flat body, ALL uniform weights in LDS, 8 waves/SIMD =================
__global__ __launch_bounds__(256, 8) void edge_tile_kernel(
    const unsigned short* __restrict__ rec,
    const _Float16* __restrict__ Ph, const _Float16* __restrict__ QH,
    const float* __restrict__ dis,
    const _Float16* __restrict__ w2p, const float* __restrict__ b2,
    const float* __restrict__ w1e, const float* __restrict__ w3,
    const float* __restrict__ b3,
    float* __restrict__ aggr, float* __restrict__ stats, int EN)
{
  __shared__ _Float16 sB[4096];   // w2 B-frags
  __shared__ _Float16 sW1[64];    // w1 edge-attr row (f16)
  __shared__ float sw3b2[128];    // [0:64) w3, [64:128) b2
  if (blockIdx.x == 0 && threadIdx.x < 128) stats[threadIdx.x] = 0.f;
  for (int i = threadIdx.x; i < 512; i += 256)
    ((half8*)sB)[i] = ((const half8*)w2p)[i];
  if (threadIdx.x < 64){
    sW1[threadIdx.x] = (_Float16)w1e[threadIdx.x];
    sw3b2[threadIdx.x]      = w3[threadIdx.x];
    sw3b2[64 + threadIdx.x] = b2[threadIdx.x];
  }
  __syncthreads();

  const int lane = threadIdx.x & 63;
  const int g16  = lane >> 4;
  const int l16  = lane & 15;
  const float b3v = b3[0];
  const _Float16* QHh = QH + 64;

  int wid = (blockIdx.x*blockDim.x + threadIdx.x) >> 6;
  int nw  = (gridDim.x*blockDim.x) >> 6;
  int tiles = (EN + 15) >> 4;

  for (int tile = wid; tile < tiles; tile += nw){
    int e0 = tile << 4;
    int m = EN - e0; if (m > 16) m = 16;
    int el = e0 + ((l16 < m) ? l16 : (m-1));
    size_t b3i = (size_t)el*3;
    int r = rec[b3i];
    int c = rec[b3i+1];
    hu16 cv; cv.u = rec[b3i+2];
    _Float16 eavh = cv.f;
    float dv = (l16 < m) ? dis[r] : 0.0f;   // 0-weight for clamped lanes

    half8 hq0 = *(const half8*)(QH + (size_t)r*128 + g16*8);
    half8 hq1 = *(const half8*)(QH + (size_t)r*128 + 32 + g16*8);
    half8 p0  = *(const half8*)(Ph + (size_t)c*64 + g16*8);
    half8 p1  = *(const half8*)(Ph + (size_t)c*64 + 32 + g16*8);

    // batched h-gathers, issued before compute consumes anything
    _Float16 hv16[16];
    #pragma unroll
    for (int i = 0; i < 16; ++i){
      int ri = __builtin_amdgcn_readlane(r, i);
      hv16[i] = QHh[(size_t)ri*128 + lane];
    }

    // packed-f16 A-frag build (w1 row from LDS broadcast)
    half8 w1a = *(const half8*)&sW1[g16*8];
    half8 w1b = *(const half8*)&sW1[32 + g16*8];
    half8 e8;
    #pragma unroll
    for (int j = 0; j < 8; ++j) e8[j] = eavh;
    half8 a0h = p0 + hq0 + w1a*e8;
    half8 a1h = p1 + hq1 + w1b*e8;
    #pragma unroll
    for (int j = 0; j < 8; ++j){
      a0h[j] = a0h[j] > (_Float16)0.f ? a0h[j] : (_Float16)0.f;
      a1h[j] = a1h[j] > (_Float16)0.f ? a1h[j] : (_Float16)0.f;
    }

    floatx4 acc[4];
    #pragma unroll
    for (int t4 = 0; t4 < 4; ++t4){
      float b2v = sw3b2[64 + t4*16 + l16];
      acc[t4] = (floatx4){b2v, b2v, b2v, b2v};
    }
    __builtin_amdgcn_s_setprio(1);
    #pragma unroll
    for (int t4 = 0; t4 < 4; ++t4){
      half8 bf0 = *(const half8*)&sB[t4*1024 + g16*128 + l16*8];
      half8 bf1 = *(const half8*)&sB[t4*1024 + 512 + g16*128 + l16*8];
      acc[t4] = __builtin_amdgcn_mfma_f32_16x16x32_f16(a0h, bf0, acc[t4], 0, 0, 0);
      acc[t4] = __builtin_amdgcn_mfma_f32_16x16x32_f16(a1h, bf1, acc[t4], 0, 0, 0);
    }
    __builtin_amdgcn_s_setprio(0);

    float s[4] = {0.f,0.f,0.f,0.f};
    #pragma unroll
    for (int t4 = 0; t4 < 4; ++t4){
      float w3v = sw3b2[t4*16 + l16];
      #pragma unroll
      for (int rg = 0; rg < 4; ++rg)
        s[rg] += fmaxf(acc[t4][rg], 0.0f) * w3v;
    }
    #pragma unroll
    for (int rg = 0; rg < 4; ++rg){
      #pragma unroll
      for (int off = 1; off < 16; off <<= 1)
        s[rg] += __shfl_xor(s[rg], off);
      s[rg] = sigmoidf_(s[rg] + b3v);
    }

    // per-edge factor f = gate * dis
    float fs[4];
    #pragma unroll
    for (int rg = 0; rg < 4; ++rg){
      float dvp = __shfl(dv, (g16 << 4) | (g16*4 + rg));
      fs[rg] = s[rg] * dvp;
    }

    // segment-boundary mask (c non-decreasing; force flush at i=15)
    int cnext = __shfl(c, (lane & 48) | ((l16 + 1) & 15));
    unsigned long long bm = __ballot(c != cnext);
    unsigned bmask = ((unsigned)bm | 0x8000u) & 0xffffu;

    float accv = 0.f;
    #pragma unroll
    for (int i = 0; i < 16; ++i){
      float gi = bcast_(fs[i & 3], (i >> 2) << 4);
      accv = fmaf(gi, (float)hv16[i], accv);
      if ((bmask >> i) & 1){
        int ci = __builtin_amdgcn_readlane(c, i);
        atomicAdd(&aggr[(size_t)ci*64 + lane], accv);
        accv = 0.f;
      }
    }
  }
}

// ================= fc2 with inline fc1-norm+relu =================
__global__ __launch_bounds__(256) void fc2_kernel(
    const float* __restrict__ x, const float* __restrict__ stats,
    const float* __restrict__ gw, const float* __restrict__ gb,
    const float* __restrict__ gms,
    const float* __restrict__ w, const float* __restrict__ b,
    float* __restrict__ out, int n){
  __shared__ float sSO[128];
  __shared__ float sW[128];
  if (threadIdx.x < 64){
    int ch = threadIdx.x;
    float invN = 1.0f/(float)n;
    float mean = stats[ch]*invN;
    float mm = mean*gms[ch];
    float var = stats[64+ch]*invN - mm*(2.0f*mean - mm);
    float inv = rsqrtf(fmaxf(var,0.f)+GN_EPS);
    float sc = inv*gw[ch];
    sSO[ch] = sc;
    sSO[64+ch] = gb[ch] - mm*sc;
  }
  for (int k = threadIdx.x; k < 128; k += 256) sW[k] = w[k];
  __syncthreads();
  int i = blockIdx.x*blockDim.x + threadIdx.x;
  if (i >= n) return;
  float a0 = b[0], a1 = b[1];
  const float4* xr = (const float4*)(x + (size_t)i*64);
  #pragma unroll
  for (int k4 = 0; k4 < 16; ++k4){
    float4 v = xr[k4];
    float vv[4] = {v.x, v.y, v.z, v.w};
    #pragma unroll
    for (int j = 0; j < 4; ++j){
      int k = k4*4 + j;
      float u = fmaxf(vv[j]*sSO[k] + sSO[64+k], 0.f);
      a0 += u*sW[k*2+0];
      a1 += u*sW[k*2+1];
    }
  }
  out[i*2+0] = a0;
  out[i*2+1] = a1;
}

extern "C" void kernel_launch(void* const* d_in, const int* in_sizes, int n_in,
                              void* d_out, int out_size, void* d_ws, size_t ws_size,
                              hipStream_t stream){
  const float* x          = (const float*)d_in[0];
  const int*   ei         = (const int*)  d_in[1];
  const float* ea         = (const float*)d_in[2];
  const float* preproc_w  = (const float*)d_in[4];
  const float* preproc_b  = (const float*)d_in[5];
  const float* gn_pre_w   = (const float*)d_in[6];
  const float* gn_pre_b   = (const float*)d_in[7];
  const float* gn_pre_ms  = (const float*)d_in[8];
  const float* init_w     = (const float*)d_in[9];
  const float* init_b     = (const float*)d_in[10];
  const float* gn_init_w  = (const float*)d_in[11];
  const float* gn_init_b  = (const float*)d_in[12];
  const float* gn_init_ms = (const float*)d_in[13];
  const float* gate_w1    = (const float*)d_in[14];
  const float* gate_b1    = (const float*)d_in[15];
  const float* gate_w2    = (const float*)d_in[16];
  const float* gate_b2    = (const float*)d_in[17];
  const float* gate_w3    = (const float*)d_in[18];
  const float* gate_b3    = (const float*)d_in[19];
  const float* lin_z_w    = (const float*)d_in[20];
  const float* lin_z_b    = (const float*)d_in[21];
  const float* lin_r_w    = (const float*)d_in[22];
  const float* lin_r_b    = (const float*)d_in[23];
  const float* lin_h_w    = (const float*)d_in[24];
  const float* lin_h_b    = (const float*)d_in[25];
  const float* gn_ggnn_w  = (const float*)d_in[26];
  const float* gn_ggnn_b  = (const float*)d_in[27];
  const float* gn_ggnn_ms = (const float*)d_in[28];
  const float* fc1_w      = (const float*)d_in[29];
  const float* fc1_b      = (const float*)d_in[30];
  const float* gn_fc1_w   = (const float*)d_in[31];
  const float* gn_fc1_b   = (const float*)d_in[32];
  const float* gn_fc1_ms  = (const float*)d_in[33];
  const float* fc2_w      = (const float*)d_in[34];
  const float* fc2_b      = (const float*)d_in[35];

  const int N = in_sizes[3];
  const int E = in_sizes[1] / 2;
  const int EN = E + N;

  // ---- workspace: 5 R-regions (R = 64N floats) + dis + 2 stats sets ----
  float* base = (float*)d_ws;
  const size_t R = (size_t)64*N;
  float* h     = base;
  float* h0    = h    + R;
  float* Preg  = h0   + R;        // Ph f16 [N,64] | rec (6B/edge) | wp
  float* aggr  = Preg + R;        // aggregation target; CSR scratch pre-use
  float* QHreg = aggr + R;        // f16 [N,128]: Q half + H half
  float* dis   = QHreg + R;
  float* stats = dis + N;         // 256 floats
  size_t need = (5*R + N + 256) * sizeof(float);
  if (ws_size < need || N > 65535) return;

  _Float16* Ph  = (_Float16*)Preg;
  _Float16* QH  = (_Float16*)QHreg;
  unsigned short* rec = (unsigned short*)(Preg + 32*(size_t)N);  // EN*3 ushorts
  _Float16* wp  = (_Float16*)(((uintptr_t)(rec + (size_t)EN*3) + 15) & ~(uintptr_t)15);
  _Float16* w1p = wp;           // 8192
  _Float16* gwp = wp + 8192;    // 3*8192
  _Float16* fc1p= wp + 32768;   // 8192
  _Float16* w2p = wp + 40960;   // 4096

  // CSR build scratch (in aggr region; dead after place_kernel)
  int* cnt    = (int*)aggr;
  int* loc    = cnt + N;
  int* bsum   = loc + N;        // 256
  int* rowptr = bsum + 256;     // N+1
  int* rank   = rowptr + (N+1); // EN ints

  const int GB = 1024;
  const int RB = 784;    // 3136 waves >= 3125 node tiles
  const int EB = 3072;
  const int nb = (N + 255) / 256;

  // ---- CSR build (single atomic pass) + weight repack ----
  hipMemsetAsync(cnt, 0, (size_t)N*sizeof(int), stream);
  rank_kernel<<<(EN+255)/256, 256, 0, stream>>>(ei, cnt, rank, E, N);
  scan1_kernel<<<nb, 256, 0, stream>>>(cnt, loc, bsum, dis, N);
  scan2_kernel<<<1, 256, 0, stream>>>(bsum, nb);
  scan3_kernel<<<nb, 256, 0, stream>>>(loc, bsum, rowptr, N, EN);
  place_kernel<<<(EN+255)/256, 256, 0, stream>>>(ei, ea, rowptr, rank, rec, E, N);
  wprep_kernel<<<176, 256, 0, stream>>>(gate_w1, lin_z_w, lin_r_w, lin_h_w, fc1_w, gate_w2, wp);
  hipMemsetAsync(aggr, 0, R*sizeof(float), stream);   // once; gru re-zeroes per layer

  // ---- preproc + init ----
  hipMemsetAsync(stats, 0, 2*128*sizeof(float), stream);
  mm1_kernel<16,32,0,1><<<GB, 256, 0, stream>>>(x, preproc_w, preproc_b,
                                                nullptr, nullptr, nullptr, nullptr,
                                                h, stats, N);
  mm1_kernel<32,64,1,1><<<GB, 256, 0, stream>>>(h, init_w, init_b,
                                                stats, gn_pre_w, gn_pre_b, gn_pre_ms,
                                                h0, stats + 128, N);
  normpq_kernel<1,1><<<RB, 256, 0, stream>>>(h0, h, h0, stats + 128,
                                             gn_init_w, gn_init_b, gn_init_ms,
                                             w1p, gate_b1, Ph, QH, N);

  // ---- 4 tied GGNN layers ----
  for (int layer = 0; layer < 4; ++layer){
    edge_tile_kernel<<<EB, 256, 0, stream>>>(rec, Ph, QH, dis,
                                             w2p, gate_b2, gate_w1 + 128*64,
                                             gate_w3, gate_b3, aggr, stats, EN);
    gru_mfma_kernel<<<RB, 256, 0, stream>>>(h, aggr, dis, QH, gwp,
                                            lin_z_b, lin_r_b, lin_h_b, stats, N);
    if (layer < 3)
      normpq_kernel<0,0><<<RB, 256, 0, stream>>>(h, h, nullptr, stats,
                                                 gn_ggnn_w, gn_ggnn_b, gn_ggnn_ms,
                                                 w1p, gate_b1, Ph, QH, N);
    // layer 3: h stays RAW; ggnn-norm applied inline inside fc1
  }

  // ---- fc1 (MFMA + inline ggnn-norm on h + fused stats; stats+128 pre-zeroed by gru) ----
  fc1_mfma_kernel<<<RB, 256, 0, stream>>>(h0, h, stats,
                                          gn_ggnn_w, gn_ggnn_b, gn_ggnn_ms,
                                          fc1p, fc1_b, aggr, stats + 128, N);

  // ---- fc2 (inline fc1-norm + relu) ----
  fc2_kernel<<<(N+255)/256, 256, 0, stream>>>(aggr, stats + 128,
                                              gn_fc1_w, gn_fc1_b, gn_fc1_ms,
                                              fc2_w, fc2_b, (float*)d_out, N);
}

// Round 13
// 590.944 us; speedup vs baseline: 2.0219x; 2.0219x over previous
//
#include <hip/hip_runtime.h>

#define GN_EPS 1e-5f

typedef _Float16 half8 __attribute__((ext_vector_type(8)));
typedef float floatx4 __attribute__((ext_vector_type(4)));

__device__ __forceinline__ float sigmoidf_(float x){ return 1.0f/(1.0f+__expf(-x)); }
__device__ __forceinline__ float bcast_(float v, int k){
  return __int_as_float(__builtin_amdgcn_readlane(__float_as_int(v), k));
}
union hu16 { unsigned short u; _Float16 f; };

// ================= CSR build (rank-fused: single atomic pass) =================
__global__ void rank_kernel(const int* __restrict__ ei, int* cnt, int* rank,
                            int E, int n){
  int i = blockIdx.x*blockDim.x+threadIdx.x;
  int tot = E + n;
  if (i >= tot) return;
  int c = (i < E) ? ei[E+i] : (i - E);
  rank[i] = atomicAdd(&cnt[c], 1);
}
__global__ __launch_bounds__(256) void scan1_kernel(const int* __restrict__ cnt,
                                                    int* loc, int* bsum,
                                                    float* __restrict__ dis, int n){
  __shared__ int s[256];
  int t = threadIdx.x, i = blockIdx.x*256 + t;
  int v = (i < n) ? cnt[i] : 0;
  if (i < n) dis[i] = rsqrtf((float)v);
  s[t] = v; __syncthreads();
  #pragma unroll
  for (int d = 1; d < 256; d <<= 1){
    int u = (t >= d) ? s[t-d] : 0; __syncthreads();
    s[t] += u; __syncthreads();
  }
  if (i < n) loc[i] = s[t] - v;
  if (t == 255) bsum[blockIdx.x] = s[255];
}
__global__ __launch_bounds__(256) void scan2_kernel(int* bsum, int nb){
  __shared__ int s[256];
  int t = threadIdx.x;
  int v = (t < nb) ? bsum[t] : 0;
  s[t] = v; __syncthreads();
  #pragma unroll
  for (int d = 1; d < 256; d <<= 1){
    int u = (t >= d) ? s[t-d] : 0; __syncthreads();
    s[t] += u; __syncthreads();
  }
  if (t < nb) bsum[t] = s[t] - v;
}
__global__ void scan3_kernel(const int* __restrict__ loc, const int* __restrict__ bsum,
                             int* rowptr, int n, int total){
  int i = blockIdx.x*blockDim.x+threadIdx.x;
  if (i < n) rowptr[i] = loc[i] + bsum[i >> 8];
  if (i == 0) rowptr[n] = total;
}
// pass 2: NO atomics — j = rowptr[c] + rank[i]; rec 6B/edge {r, c, ea(f16)}
__global__ void place_kernel(const int* __restrict__ ei, const float* __restrict__ ea,
                             const int* __restrict__ rowptr, const int* __restrict__ rank,
                             unsigned short* rec, int E, int n){
  int idx = blockIdx.x*blockDim.x+threadIdx.x;
  int tot = E + n;
  if (idx >= tot) return;
  int r, c; float v;
  if (idx < E){ r = ei[idx]; c = ei[E+idx]; v = ea[idx]; }
  else        { r = c = idx - E; v = 1.0f; }
  int j = rowptr[c] + rank[idx];
  hu16 cv; cv.f = (_Float16)v;
  size_t b3 = (size_t)j*3;
  rec[b3]   = (unsigned short)r;
  rec[b3+1] = (unsigned short)c;
  rec[b3+2] = cv.u;
}

// ================= weight repack (f16, MFMA-fragment order) =================
__global__ __launch_bounds__(256) void wprep_kernel(
    const float* __restrict__ w1, const float* __restrict__ zw,
    const float* __restrict__ rw, const float* __restrict__ hw,
    const float* __restrict__ fw, const float* __restrict__ w2,
    _Float16* __restrict__ wp){
  int idx = blockIdx.x*256 + threadIdx.x;
  if (idx < 8192){
    int t=idx>>10, kh=(idx>>9)&1, g=(idx>>7)&3, l=(idx>>3)&15, j=idx&7;
    int kg=(t>=4?64:0)+kh*32+g*8+j;
    wp[idx] = (_Float16)w1[kg*64 + (t&3)*16 + l];
  } else if (idx < 40960){
    int m=(idx-8192)>>13, k=(idx-8192)&8191;
    int t=(k>>11)&3, kh=(k>>9)&3, g=(k>>7)&3, l=(k>>3)&15, j=k&7;
    const float* W = (m==0)?zw:((m==1)?rw:((m==2)?hw:fw));
    wp[idx] = (_Float16)W[(kh*32+g*8+j)*64 + t*16 + l];
  } else if (idx < 45056){
    int k = idx-40960;
    int t=(k>>10)&3, kh=(k>>9)&1, g=(k>>7)&3, l=(k>>3)&15, j=k&7;
    wp[idx] = (_Float16)w2[(kh*32+g*8+j)*64 + t*16 + l];
  }
}

// ================= small node matvec + optional inline input-norm + fused stats =================
template<int K_IN, int C_OUT, int NORMIN, int STATS>
__global__ __launch_bounds__(256) void mm1_kernel(
    const float* __restrict__ x, const float* __restrict__ W,
    const float* __restrict__ b,
    const float* __restrict__ nstats, const float* __restrict__ nw,
    const float* __restrict__ nb, const float* __restrict__ nms,
    float* __restrict__ y, float* __restrict__ stats, int n){
  __shared__ float sW[K_IN*C_OUT];
  __shared__ float sSt[2*C_OUT];
  __shared__ float sIN[2*K_IN];
  if (STATS && threadIdx.x < 2*C_OUT) sSt[threadIdx.x] = 0.f;
  if (NORMIN && threadIdx.x < K_IN){
    int ch = threadIdx.x;
    float invN = 1.0f/(float)n;
    float mean = nstats[ch]*invN;
    float mm = mean*nms[ch];
    float var = nstats[K_IN+ch]*invN - mm*(2.0f*mean - mm);
    float inv = rsqrtf(fmaxf(var,0.f)+GN_EPS);
    float sc = inv*nw[ch];
    sIN[ch] = sc;
    sIN[K_IN+ch] = nb[ch] - mm*sc;
  }
  for (int i = threadIdx.x; i < K_IN*C_OUT; i += 256) sW[i] = W[i];
  __syncthreads();
  const int lane = threadIdx.x & 63;
  const int col  = (lane < C_OUT) ? lane : 0;
  const float bias = b[col];
  float isc = 1.f, iof = 0.f;
  if (NORMIN && lane < K_IN){ isc = sIN[lane]; iof = sIN[K_IN+lane]; }
  int wid = (blockIdx.x*256 + threadIdx.x) >> 6;
  int nw_ = (gridDim.x*256) >> 6;
  float qs = 0.f, qq = 0.f;
  for (int i = wid; i < n; i += nw_){
    float xv = (lane < K_IN) ? x[(size_t)i*K_IN + lane] : 0.0f;
    if (NORMIN) xv = fmaxf(xv*isc + iof, 0.f);
    float a0 = bias, a1 = 0.0f;
    #pragma unroll
    for (int k = 0; k < K_IN; k += 2){
      a0 += bcast_(xv, k  ) * sW[(k  )*C_OUT + col];
      a1 += bcast_(xv, k+1) * sW[(k+1)*C_OUT + col];
    }
    if (lane < C_OUT){
      float v = a0 + a1;
      y[(size_t)i*C_OUT + lane] = v;
      if (STATS){ qs += v; qq += v*v; }
    }
  }
  if (STATS){
    if (lane < C_OUT){
      atomicAdd(&sSt[lane], qs);
      atomicAdd(&sSt[C_OUT+lane], qq);
    }
    __syncthreads();
    if (threadIdx.x < 2*C_OUT) atomicAdd(&stats[threadIdx.x], sSt[threadIdx.x]);
  }
}

// ================= fused GraphNorm-apply + pq via MFMA =================
template<int RELU, int WRITE_H0>
__global__ __launch_bounds__(256) void normpq_kernel(
    const float* __restrict__ hin, float* __restrict__ hout,
    float* __restrict__ h0out,
    const float* __restrict__ stats,
    const float* __restrict__ gw, const float* __restrict__ gb,
    const float* __restrict__ gms,
    const _Float16* __restrict__ w1p, const float* __restrict__ b1,
    _Float16* __restrict__ Ph, _Float16* __restrict__ QH, int n)
{
  __shared__ _Float16 sB[8192];
  __shared__ float sSO[128];
  for (int i = threadIdx.x; i < 1024; i += 256)
    ((half8*)sB)[i] = ((const half8*)w1p)[i];
  if (threadIdx.x < 64){
    int ch = threadIdx.x;
    float invN = 1.0f/(float)n;
    float mean = stats[ch]*invN;
    float mm = mean*gms[ch];
    float var = stats[64+ch]*invN - mm*(2.0f*mean - mm);
    float inv = rsqrtf(fmaxf(var,0.f)+GN_EPS);
    float sc = inv*gw[ch];
    sSO[ch] = sc;
    sSO[64+ch] = gb[ch] - mm*sc;
  }
  __syncthreads();
  const int lane = threadIdx.x & 63;
  const int g16 = lane>>4, l16 = lane&15;
  float scA[8], ofA[8], scB[8], ofB[8];
  #pragma unroll
  for (int j = 0; j < 8; ++j){
    scA[j]=sSO[g16*8+j];    ofA[j]=sSO[64+g16*8+j];
    scB[j]=sSO[32+g16*8+j]; ofB[j]=sSO[96+g16*8+j];
  }
  float b1f[4];
  #pragma unroll
  for (int t = 0; t < 4; ++t) b1f[t] = b1[t*16 + l16];

  int wid = (blockIdx.x*blockDim.x + threadIdx.x) >> 6;
  int nw  = (gridDim.x*blockDim.x) >> 6;
  int tiles = (n + 15) >> 4;
  for (int tile = wid; tile < tiles; tile += nw){
    int base = tile*16;
    int na = min(base + l16, n-1);
    const float* hp = hin + (size_t)na*64;
    float4 a0 = *(const float4*)(hp + g16*8);
    float4 a1 = *(const float4*)(hp + g16*8 + 4);
    float4 c0 = *(const float4*)(hp + 32 + g16*8);
    float4 c1 = *(const float4*)(hp + 32 + g16*8 + 4);
    float va[8] = {a0.x,a0.y,a0.z,a0.w,a1.x,a1.y,a1.z,a1.w};
    float vb[8] = {c0.x,c0.y,c0.z,c0.w,c1.x,c1.y,c1.z,c1.w};
    half8 af0, af1;
    #pragma unroll
    for (int j = 0; j < 8; ++j){
      float v = va[j]*scA[j] + ofA[j];
      if (RELU) v = fmaxf(v, 0.f);
      va[j] = v; af0[j] = (_Float16)v;
      float u = vb[j]*scB[j] + ofB[j];
      if (RELU) u = fmaxf(u, 0.f);
      vb[j] = u; af1[j] = (_Float16)u;
    }
    float* op = hout + (size_t)na*64;
    *(float4*)(op + g16*8)       = (float4){va[0],va[1],va[2],va[3]};
    *(float4*)(op + g16*8 + 4)   = (float4){va[4],va[5],va[6],va[7]};
    *(float4*)(op + 32 + g16*8)  = (float4){vb[0],vb[1],vb[2],vb[3]};
    *(float4*)(op + 32 + g16*8+4)= (float4){vb[4],vb[5],vb[6],vb[7]};
    if (WRITE_H0){
      float* o2 = h0out + (size_t)na*64;
      *(float4*)(o2 + g16*8)       = (float4){va[0],va[1],va[2],va[3]};
      *(float4*)(o2 + g16*8 + 4)   = (float4){va[4],va[5],va[6],va[7]};
      *(float4*)(o2 + 32 + g16*8)  = (float4){vb[0],vb[1],vb[2],vb[3]};
      *(float4*)(o2 + 32 + g16*8+4)= (float4){vb[4],vb[5],vb[6],vb[7]};
    }
    *(half8*)(QH + (size_t)na*128 + 64 + g16*8) = af0;
    *(half8*)(QH + (size_t)na*128 + 96 + g16*8) = af1;

    floatx4 acc[8];
    #pragma unroll
    for (int t = 0; t < 8; ++t){
      float bv = (t < 4) ? b1f[t] : 0.0f;
      acc[t] = (floatx4){bv, bv, bv, bv};
    }
    #pragma unroll
    for (int t = 0; t < 8; ++t){
      half8 bf0 = *(const half8*)&sB[((t*2+0)*4+g16)*128 + l16*8];
      half8 bf1 = *(const half8*)&sB[((t*2+1)*4+g16)*128 + l16*8];
      acc[t] = __builtin_amdgcn_mfma_f32_16x16x32_f16(af0, bf0, acc[t], 0, 0, 0);
      acc[t] = __builtin_amdgcn_mfma_f32_16x16x32_f16(af1, bf1, acc[t], 0, 0, 0);
    }
    #pragma unroll
    for (int t = 0; t < 8; ++t)
      #pragma unroll
      for (int rg = 0; rg < 4; ++rg){
        int nd = base + g16*4 + rg;
        if (nd < n){
          if (t < 4) Ph[(size_t)nd*64  + t*16 + l16]      = (_Float16)acc[t][rg];
          else       QH[(size_t)nd*128 + (t-4)*16 + l16]  = (_Float16)acc[t][rg];
        }
      }
  }
}

// ================= fused GRU via MFMA + GraphNorm stats (+aggr & stats2 zeroing) =================
__global__ __launch_bounds__(256) void gru_mfma_kernel(
    float* __restrict__ h, float* __restrict__ aggr,
    const float* __restrict__ dis, const _Float16* __restrict__ QH,
    const _Float16* __restrict__ gwp,
    const float* __restrict__ zb, const float* __restrict__ rb,
    const float* __restrict__ hb,
    float* __restrict__ stats, int n)
{
  __shared__ _Float16 sW[3*8192];
  __shared__ _Float16 sRH[4][16][72];
  __shared__ float sSt[128];
  if (threadIdx.x < 128) sSt[threadIdx.x] = 0.f;
  if (blockIdx.x == 0 && threadIdx.x < 128) stats[128 + threadIdx.x] = 0.f;  // pre-zero fc1 stats
  for (int i = threadIdx.x; i < 3072; i += 256)
    ((half8*)sW)[i] = ((const half8*)gwp)[i];
  __syncthreads();
  const int lane = threadIdx.x & 63;
  const int g16 = lane>>4, l16 = lane&15;
  const int w = threadIdx.x >> 6;
  float zbf[4], rbf[4], hbf[4];
  #pragma unroll
  for (int t = 0; t < 4; ++t){
    zbf[t] = zb[t*16+l16]; rbf[t] = rb[t*16+l16]; hbf[t] = hb[t*16+l16];
  }
  float ssum[4] = {0,0,0,0}, ssq[4] = {0,0,0,0};
#define GW(m,t,kh) (*(const half8*)&sW[(m)*8192 + (((t)*4+(kh))*4+g16)*128 + l16*8])

  int wid = (blockIdx.x*blockDim.x + threadIdx.x) >> 6;
  int nw  = (gridDim.x*blockDim.x) >> 6;
  int tiles = (n + 15) >> 4;
  for (int tile = wid; tile < tiles; tile += nw){
    int base = tile*16;
    int na = min(base + l16, n-1);
    float dv = dis[na];
    half8 af[4];
    af[0] = *(const half8*)(QH + (size_t)na*128 + 64 + g16*8);
    af[1] = *(const half8*)(QH + (size_t)na*128 + 96 + g16*8);
    #pragma unroll
    for (int kh = 0; kh < 2; ++kh){
      float* ar = aggr + (size_t)na*64 + kh*32 + g16*8;
      float4 a0 = *(const float4*)ar;
      float4 a1 = *(const float4*)(ar+4);
      *(float4*)(ar)   = (float4){0,0,0,0};
      *(float4*)(ar+4) = (float4){0,0,0,0};
      half8 t8;
      t8[0]=(_Float16)(a0.x*dv); t8[1]=(_Float16)(a0.y*dv);
      t8[2]=(_Float16)(a0.z*dv); t8[3]=(_Float16)(a0.w*dv);
      t8[4]=(_Float16)(a1.x*dv); t8[5]=(_Float16)(a1.y*dv);
      t8[6]=(_Float16)(a1.z*dv); t8[7]=(_Float16)(a1.w*dv);
      af[2+kh] = t8;
    }
    floatx4 az[4], ar4[4];
    #pragma unroll
    for (int t = 0; t < 4; ++t){
      az[t]  = (floatx4){zbf[t], zbf[t], zbf[t], zbf[t]};
      ar4[t] = (floatx4){rbf[t], rbf[t], rbf[t], rbf[t]};
      #pragma unroll
      for (int kh = 0; kh < 4; ++kh){
        az[t]  = __builtin_amdgcn_mfma_f32_16x16x32_f16(af[kh], GW(0,t,kh), az[t],  0, 0, 0);
        ar4[t] = __builtin_amdgcn_mfma_f32_16x16x32_f16(af[kh], GW(1,t,kh), ar4[t], 0, 0, 0);
      }
    }
    float zr[16], hv[16];
    #pragma unroll
    for (int t = 0; t < 4; ++t)
      #pragma unroll
      for (int rg = 0; rg < 4; ++rg){
        int ndc = min(base + g16*4 + rg, n-1);
        float hval = h[(size_t)ndc*64 + t*16 + l16];
        float zv = sigmoidf_(az[t][rg]);
        float rv = sigmoidf_(ar4[t][rg]);
        zr[t*4+rg] = zv; hv[t*4+rg] = hval;
        sRH[w][g16*4+rg][t*16+l16] = (_Float16)(rv*hval);
      }
    asm volatile("s_waitcnt lgkmcnt(0)" ::: "memory");
    __builtin_amdgcn_sched_barrier(0);
    half8 af2_0 = *(const half8*)&sRH[w][l16][g16*8];
    half8 af2_1 = *(const half8*)&sRH[w][l16][32 + g16*8];
    floatx4 ah[4];
    #pragma unroll
    for (int t = 0; t < 4; ++t){
      ah[t] = (floatx4){hbf[t], hbf[t], hbf[t], hbf[t]};
      ah[t] = __builtin_amdgcn_mfma_f32_16x16x32_f16(af2_0, GW(2,t,0), ah[t], 0, 0, 0);
      ah[t] = __builtin_amdgcn_mfma_f32_16x16x32_f16(af2_1, GW(2,t,1), ah[t], 0, 0, 0);
      ah[t] = __builtin_amdgcn_mfma_f32_16x16x32_f16(af[2],  GW(2,t,2), ah[t], 0, 0, 0);
      ah[t] = __builtin_amdgcn_mfma_f32_16x16x32_f16(af[3],  GW(2,t,3), ah[t], 0, 0, 0);
    }
    #pragma unroll
    for (int t = 0; t < 4; ++t)
      #pragma unroll
      for (int rg = 0; rg < 4; ++rg){
        int nd = base + g16*4 + rg;
        if (nd < n){
          float hc = fmaxf(ah[t][rg], 0.f);
          float zv = zr[t*4+rg];
          float hn = (1.f - zv)*hv[t*4+rg] + zv*hc;
          h[(size_t)nd*64 + t*16 + l16] = hn;
          ssum[t] += hn; ssq[t] += hn*hn;
        }
      }
  }
#undef GW
  #pragma unroll
  for (int t = 0; t < 4; ++t){
    atomicAdd(&sSt[t*16+l16], ssum[t]);
    atomicAdd(&sSt[64+t*16+l16], ssq[t]);
  }
  __syncthreads();
  if (threadIdx.x < 128) atomicAdd(&stats[threadIdx.x], sSt[threadIdx.x]);
}

// ================= fc1 via MFMA + inline ggnn-norm on h + fused stats =================
__global__ __launch_bounds__(256) void fc1_mfma_kernel(
    const float* __restrict__ h0, const float* __restrict__ h,
    const float* __restrict__ hstats,
    const float* __restrict__ gw, const float* __restrict__ gb,
    const float* __restrict__ gms,
    const _Float16* __restrict__ fp, const float* __restrict__ b,
    float* __restrict__ out, float* __restrict__ stats, int n)
{
  __shared__ _Float16 sB[8192];
  __shared__ float sSt[128];
  __shared__ float sSO[128];
  if (threadIdx.x < 128) sSt[threadIdx.x] = 0.f;
  if (threadIdx.x < 64){
    int ch = threadIdx.x;
    float invN = 1.0f/(float)n;
    float mean = hstats[ch]*invN;
    float mm = mean*gms[ch];
    float var = hstats[64+ch]*invN - mm*(2.0f*mean - mm);
    float inv = rsqrtf(fmaxf(var,0.f)+GN_EPS);
    float sc = inv*gw[ch];
    sSO[ch] = sc;
    sSO[64+ch] = gb[ch] - mm*sc;
  }
  for (int i = threadIdx.x; i < 1024; i += 256)
    ((half8*)sB)[i] = ((const half8*)fp)[i];
  __syncthreads();
  const int lane = threadIdx.x & 63;
  const int g16 = lane>>4, l16 = lane&15;
  float bf[4];
  #pragma unroll
  for (int t = 0; t < 4; ++t) bf[t] = b[t*16+l16];
  float scH[16], ofH[16];
  #pragma unroll
  for (int j = 0; j < 8; ++j){
    scH[j]   = sSO[g16*8+j];    ofH[j]   = sSO[64+g16*8+j];
    scH[8+j] = sSO[32+g16*8+j]; ofH[8+j] = sSO[96+g16*8+j];
  }
  float ssum[4] = {0,0,0,0}, ssq[4] = {0,0,0,0};

  int wid = (blockIdx.x*blockDim.x + threadIdx.x) >> 6;
  int nw  = (gridDim.x*blockDim.x) >> 6;
  int tiles = (n + 15) >> 4;
  for (int tile = wid; tile < tiles; tile += nw){
    int base = tile*16;
    int na = min(base + l16, n-1);
    half8 af[4];
    #pragma unroll
    for (int kh = 0; kh < 4; ++kh){
      const float* sp = (kh < 2 ? h0 : h) + (size_t)na*64 + (kh&1)*32 + g16*8;
      float4 a0 = *(const float4*)sp;
      float4 a1 = *(const float4*)(sp+4);
      float v[8] = {a0.x,a0.y,a0.z,a0.w,a1.x,a1.y,a1.z,a1.w};
      half8 t8;
      if (kh < 2){
        #pragma unroll
        for (int j = 0; j < 8; ++j) t8[j] = (_Float16)v[j];
      } else {
        #pragma unroll
        for (int j = 0; j < 8; ++j)
          t8[j] = (_Float16)(v[j]*scH[(kh&1)*8+j] + ofH[(kh&1)*8+j]);
      }
      af[kh] = t8;
    }
    #pragma unroll
    for (int t = 0; t < 4; ++t){
      floatx4 acc = (floatx4){bf[t], bf[t], bf[t], bf[t]};
      #pragma unroll
      for (int kh = 0; kh < 4; ++kh)
        acc = __builtin_amdgcn_mfma_f32_16x16x32_f16(af[kh],
                *(const half8*)&sB[((t*4+kh)*4+g16)*128 + l16*8], acc, 0, 0, 0);
      #pragma unroll
      for (int rg = 0; rg < 4; ++rg){
        int nd = base + g16*4 + rg;
        if (nd < n){
          float v = acc[rg];
          out[(size_t)nd*64 + t*16 + l16] = v;
          ssum[t] += v; ssq[t] += v*v;
        }
      }
    }
  }
  #pragma unroll
  for (int t = 0; t < 4; ++t){
    atomicAdd(&sSt[t*16+l16], ssum[t]);
    atomicAdd(&sSt[64+t*16+l16], ssq[t]);
  }
  __syncthreads();
  if (threadIdx.x < 128) atomicAdd(&stats[threadIdx.x], sSt[threadIdx.x]);
}

// ================= edge kernel: round-7 register-frag body + 6B records =================
__global__ __launch_bounds__(256) void edge_tile_kernel(
    const unsigned short* __restrict__ rec,
    const _Float16* __restrict__ Ph, const _Float16* __restrict__ QH,
    const float* __restrict__ dis,
    const _Float16* __restrict__ w2p, const float* __restrict__ b2,
    const float* __restrict__ w1e, const float* __restrict__ w3,
    const float* __restrict__ b3,
    float* __restrict__ aggr, float* __restrict__ stats, int EN)
{
  if (blockIdx.x == 0 && threadIdx.x < 128) stats[threadIdx.x] = 0.f;

  const int lane = threadIdx.x & 63;
  const int g16  = lane >> 4;
  const int l16  = lane & 15;

  half8 bfrag[4][2];
  #pragma unroll
  for (int t = 0; t < 4; ++t)
    #pragma unroll
    for (int kh = 0; kh < 2; ++kh)
      bfrag[t][kh] = *(const half8*)&w2p[t*1024 + kh*512 + g16*128 + l16*8];

  half8 w1h[2];
  #pragma unroll
  for (int kh = 0; kh < 2; ++kh)
    #pragma unroll
    for (int j = 0; j < 8; ++j)
      w1h[kh][j] = (_Float16)w1e[kh*32 + g16*8 + j];

  float w3f[4], b2f[4];
  #pragma unroll
  for (int t = 0; t < 4; ++t){ w3f[t] = w3[t*16 + l16]; b2f[t] = b2[t*16 + l16]; }
  const float b3v = b3[0];
  const _Float16* QHh = QH + 64;

  int wid = (blockIdx.x*blockDim.x + threadIdx.x) >> 6;
  int nw  = (gridDim.x*blockDim.x) >> 6;
  int tiles = (EN + 15) >> 4;

  for (int tile = wid; tile < tiles; tile += nw){
    int e0 = tile << 4;
    int m = EN - e0; if (m > 16) m = 16;
    int el = e0 + ((l16 < m) ? l16 : (m-1));
    size_t b3i = (size_t)el*3;
    int r = rec[b3i];
    int c = rec[b3i+1];
    hu16 cv; cv.u = rec[b3i+2];
    _Float16 eavh = cv.f;
    float dv = (l16 < m) ? dis[r] : 0.0f;   // 0-weight for clamped lanes

    half8 hq0 = *(const half8*)(QH + (size_t)r*128 + g16*8);
    half8 hq1 = *(const half8*)(QH + (size_t)r*128 + 32 + g16*8);
    half8 p0  = *(const half8*)(Ph + (size_t)c*64 + g16*8);
    half8 p1  = *(const half8*)(Ph + (size_t)c*64 + 32 + g16*8);

    // batched h-gathers, issued before compute consumes anything
    _Float16 hv16[16];
    #pragma unroll
    for (int i = 0; i < 16; ++i){
      int ri = __builtin_amdgcn_readlane(r, i);
      hv16[i] = QHh[(size_t)ri*128 + lane];
    }

    // packed-f16 A-frag build
    half8 e8;
    #pragma unroll
    for (int j = 0; j < 8; ++j) e8[j] = eavh;
    half8 a0h = p0 + hq0 + w1h[0]*e8;
    half8 a1h = p1 + hq1 + w1h[1]*e8;
    #pragma unroll
    for (int j = 0; j < 8; ++j){
      a0h[j] = a0h[j] > (_Float16)0.f ? a0h[j] : (_Float16)0.f;
      a1h[j] = a1h[j] > (_Float16)0.f ? a1h[j] : (_Float16)0.f;
    }

    floatx4 acc[4];
    #pragma unroll
    for (int t4 = 0; t4 < 4; ++t4)
      acc[t4] = (floatx4){b2f[t4], b2f[t4], b2f[t4], b2f[t4]};
    __builtin_amdgcn_s_setprio(1);
    #pragma unroll
    for (int t4 = 0; t4 < 4; ++t4){
      acc[t4] = __builtin_amdgcn_mfma_f32_16x16x32_f16(a0h, bfrag[t4][0], acc[t4], 0, 0, 0);
      acc[t4] = __builtin_amdgcn_mfma_f32_16x16x32_f16(a1h, bfrag[t4][1], acc[t4], 0, 0, 0);
    }
    __builtin_amdgcn_s_setprio(0);

    float s[4] = {0.f,0.f,0.f,0.f};
    #pragma unroll
    for (int t4 = 0; t4 < 4; ++t4)
      #pragma unroll
      for (int rg = 0; rg < 4; ++rg)
        s[rg] += fmaxf(acc[t4][rg], 0.0f) * w3f[t4];
    #pragma unroll
    for (int rg = 0; rg < 4; ++rg){
      #pragma unroll
      for (int off = 1; off < 16; off <<= 1)
        s[rg] += __shfl_xor(s[rg], off);
      s[rg] = sigmoidf_(s[rg] + b3v);
    }

    // per-edge factor f = gate * dis
    float fs[4];
    #pragma unroll
    for (int rg = 0; rg < 4; ++rg){
      float dvp = __shfl(dv, (g16 << 4) | (g16*4 + rg));
      fs[rg] = s[rg] * dvp;
    }

    // segment-boundary mask (c non-decreasing; force flush at i=15)
    int cnext = __shfl(c, (lane & 48) | ((l16 + 1) & 15));
    unsigned long long bm = __ballot(c != cnext);
    unsigned bmask = ((unsigned)bm | 0x8000u) & 0xffffu;

    float accv = 0.f;
    #pragma unroll
    for (int i = 0; i < 16; ++i){
      float gi = bcast_(fs[i & 3], (i >> 2) << 4);
      accv = fmaf(gi, (float)hv16[i], accv);
      if ((bmask >> i) & 1){
        int ci = __builtin_amdgcn_readlane(c, i);
        atomicAdd(&aggr[(size_t)ci*64 + lane], accv);
        accv = 0.f;
      }
    }
  }
}

// ================= fc2 with inline fc1-norm+relu =================
__global__ __launch_bounds__(256) void fc2_kernel(
    const float* __restrict__ x, const float* __restrict__ stats,
    const float* __restrict__ gw, const float* __restrict__ gb,
    const float* __restrict__ gms,
    const float* __restrict__ w, const float* __restrict__ b,
    float* __restrict__ out, int n){
  __shared__ float sSO[128];
  __shared__ float sW[128];
  if (threadIdx.x < 64){
    int ch = threadIdx.x;
    float invN = 1.0f/(float)n;
    float mean = stats[ch]*invN;
    float mm = mean*gms[ch];
    float var = stats[64+ch]*invN - mm*(2.0f*mean - mm);
    float inv = rsqrtf(fmaxf(var,0.f)+GN_EPS);
    float sc = inv*gw[ch];
    sSO[ch] = sc;
    sSO[64+ch] = gb[ch] - mm*sc;
  }
  for (int k = threadIdx.x; k < 128; k += 256) sW[k] = w[k];
  __syncthreads();
  int i = blockIdx.x*blockDim.x + threadIdx.x;
  if (i >= n) return;
  float a0 = b[0], a1 = b[1];
  const float4* xr = (const float4*)(x + (size_t)i*64);
  #pragma unroll
  for (int k4 = 0; k4 < 16; ++k4){
    float4 v = xr[k4];
    float vv[4] = {v.x, v.y, v.z, v.w};
    #pragma unroll
    for (int j = 0; j < 4; ++j){
      int k = k4*4 + j;
      float u = fmaxf(vv[j]*sSO[k] + sSO[64+k], 0.f);
      a0 += u*sW[k*2+0];
      a1 += u*sW[k*2+1];
    }
  }
  out[i*2+0] = a0;
  out[i*2+1] = a1;
}

extern "C" void kernel_launch(void* const* d_in, const int* in_sizes, int n_in,
                              void* d_out, int out_size, void* d_ws, size_t ws_size,
                              hipStream_t stream){
  const float* x          = (const float*)d_in[0];
  const int*   ei         = (const int*)  d_in[1];
  const float* ea         = (const float*)d_in[2];
  const float* preproc_w  = (const float*)d_in[4];
  const float* preproc_b  = (const float*)d_in[5];
  const float* gn_pre_w   = (const float*)d_in[6];
  const float* gn_pre_b   = (const float*)d_in[7];
  const float* gn_pre_ms  = (const float*)d_in[8];
  const float* init_w     = (const float*)d_in[9];
  const float* init_b     = (const float*)d_in[10];
  const float* gn_init_w  = (const float*)d_in[11];
  const float* gn_init_b  = (const float*)d_in[12];
  const float* gn_init_ms = (const float*)d_in[13];
  const float* gate_w1    = (const float*)d_in[14];
  const float* gate_b1    = (const float*)d_in[15];
  const float* gate_w2    = (const float*)d_in[16];
  const float* gate_b2    = (const float*)d_in[17];
  const float* gate_w3    = (const float*)d_in[18];
  const float* gate_b3    = (const float*)d_in[19];
  const float* lin_z_w    = (const float*)d_in[20];
  const float* lin_z_b    = (const float*)d_in[21];
  const float* lin_r_w    = (const float*)d_in[22];
  const float* lin_r_b    = (const float*)d_in[23];
  const float* lin_h_w    = (const float*)d_in[24];
  const float* lin_h_b    = (const float*)d_in[25];
  const float* gn_ggnn_w  = (const float*)d_in[26];
  const float* gn_ggnn_b  = (const float*)d_in[27];
  const float* gn_ggnn_ms = (const float*)d_in[28];
  const float* fc1_w      = (const float*)d_in[29];
  const float* fc1_b      = (const float*)d_in[30];
  const float* gn_fc1_w   = (const float*)d_in[31];
  const float* gn_fc1_b   = (const float*)d_in[32];
  const float* gn_fc1_ms  = (const float*)d_in[33];
  const float* fc2_w      = (const float*)d_in[34];
  const float* fc2_b      = (const float*)d_in[35];

  const int N = in_sizes[3];
  const int E = in_sizes[1] / 2;
  const int EN = E + N;

  // ---- workspace: 5 R-regions (R = 64N floats) + dis + 2 stats sets ----
  float* base = (float*)d_ws;
  const size_t R = (size_t)64*N;
  float* h     = base;
  float* h0    = h    + R;
  float* Preg  = h0   + R;        // Ph f16 [N,64] | rec (6B/edge) | wp
  float* aggr  = Preg + R;        // aggregation target; CSR scratch pre-use
  float* QHreg = aggr + R;        // f16 [N,128]: Q half + H half
  float* dis   = QHreg + R;
  float* stats = dis + N;         // 256 floats
  size_t need = (5*R + N + 256) * sizeof(float);
  if (ws_size < need || N > 65535) return;

  _Float16* Ph  = (_Float16*)Preg;
  _Float16* QH  = (_Float16*)QHreg;
  unsigned short* rec = (unsigned short*)(Preg + 32*(size_t)N);  // EN*3 ushorts
  _Float16* wp  = (_Float16*)(((uintptr_t)(rec + (size_t)EN*3) + 15) & ~(uintptr_t)15);
  _Float16* w1p = wp;           // 8192
  _Float16* gwp = wp + 8192;    // 3*8192
  _Float16* fc1p= wp + 32768;   // 8192
  _Float16* w2p = wp + 40960;   // 4096

  // CSR build scratch (in aggr region; dead after place_kernel)
  int* cnt    = (int*)aggr;
  int* loc    = cnt + N;
  int* bsum   = loc + N;        // 256
  int* rowptr = bsum + 256;     // N+1
  int* rank   = rowptr + (N+1); // EN ints

  const int GB = 1024;
  const int RB = 784;    // 3136 waves >= 3125 node tiles
  const int EB = 3072;
  const int nb = (N + 255) / 256;

  // ---- CSR build (single atomic pass) + weight repack ----
  hipMemsetAsync(cnt, 0, (size_t)N*sizeof(int), stream);
  rank_kernel<<<(EN+255)/256, 256, 0, stream>>>(ei, cnt, rank, E, N);
  scan1_kernel<<<nb, 256, 0, stream>>>(cnt, loc, bsum, dis, N);
  scan2_kernel<<<1, 256, 0, stream>>>(bsum, nb);
  scan3_kernel<<<nb, 256, 0, stream>>>(loc, bsum, rowptr, N, EN);
  place_kernel<<<(EN+255)/256, 256, 0, stream>>>(ei, ea, rowptr, rank, rec, E, N);
  wprep_kernel<<<176, 256, 0, stream>>>(gate_w1, lin_z_w, lin_r_w, lin_h_w, fc1_w, gate_w2, wp);
  hipMemsetAsync(aggr, 0, R*sizeof(float), stream);   // once; gru re-zeroes per layer

  // ---- preproc + init ----
  hipMemsetAsync(stats, 0, 2*128*sizeof(float), stream);
  mm1_kernel<16,32,0,1><<<GB, 256, 0, stream>>>(x, preproc_w, preproc_b,
                                                nullptr, nullptr, nullptr, nullptr,
                                                h, stats, N);
  mm1_kernel<32,64,1,1><<<GB, 256, 0, stream>>>(h, init_w, init_b,
                                                stats, gn_pre_w, gn_pre_b, gn_pre_ms,
                                                h0, stats + 128, N);
  normpq_kernel<1,1><<<RB, 256, 0, stream>>>(h0, h, h0, stats + 128,
                                             gn_init_w, gn_init_b, gn_init_ms,
                                             w1p, gate_b1, Ph, QH, N);

  // ---- 4 tied GGNN layers ----
  for (int layer = 0; layer < 4; ++layer){
    edge_tile_kernel<<<EB, 256, 0, stream>>>(rec, Ph, QH, dis,
                                             w2p, gate_b2, gate_w1 + 128*64,
                                             gate_w3, gate_b3, aggr, stats, EN);
    gru_mfma_kernel<<<RB, 256, 0, stream>>>(h, aggr, dis, QH, gwp,
                                            lin_z_b, lin_r_b, lin_h_b, stats, N);
    if (layer < 3)
      normpq_kernel<0,0><<<RB, 256, 0, stream>>>(h, h, nullptr, stats,
                                                 gn_ggnn_w, gn_ggnn_b, gn_ggnn_ms,
                                                 w1p, gate_b1, Ph, QH, N);
    // layer 3: h stays RAW; ggnn-norm applied inline inside fc1
  }

  // ---- fc1 (MFMA + inline ggnn-norm on h + fused stats; stats+128 pre-zeroed by gru) ----
  fc1_mfma_kernel<<<RB, 256, 0, stream>>>(h0, h, stats,
                                          gn_ggnn_w, gn_ggnn_b, gn_ggnn_ms,
                                          fc1p, fc1_b, aggr, stats + 128, N);

  // ---- fc2 (inline fc1-norm + relu) ----
  fc2_kernel<<<(N+255)/256, 256, 0, stream>>>(aggr, stats + 128,
                                              gn_fc1_w, gn_fc1_b, gn_fc1_ms,
                                              fc2_w, fc2_b, (float*)d_out, N);
}